// Round 8
// baseline (384.413 us; speedup 1.0000x reference)
//
#include <hip/hip_runtime.h>
#include <stdint.h>

// SAGEConv via linearity: out = x@W1^T + b + mean_neigh(x)@W2^T
//                             = [x@W1^T + b] + mean_d( (x@W2^T)[e_d] )
// N=100000, MAX_DEG=16, D_IN=256, D_OUT=256
//
// R11: R10's one-shot DMA wave (issue 8, vmcnt(0), die) averaged only ~12KB
// in flight per CU -> still latency-bound at 4 TB/s. Fix: persistent-ish
// waves, 16 nodes each, double-buffered global_load_lds pipeline with
// COUNTED vmcnt(11) (never 0): node t+1's DMAs are issued before waiting on
// node t, so ~9KB/wave stays in flight continuously (10 waves/CU = ~90KB).
// Edge prefetch distance 2, out-row prefetch distance 1, so consuming them
// never in-order-drains the current DMAs.

#define MAX_DEG 16
#define D_IN 256
#define D_OUT 256
#define N_NODES_C 100000
#define BM 64
#define LDS_A_STRIDE 264   // 256 + 8 pad (ushort elems); row stride 528 B
#define NPW 16             // nodes per wave (100000 = 6250 waves exactly)

typedef __attribute__((ext_vector_type(8))) short bf16x8;   // 8 bf16 = 4 VGPRs
typedef __attribute__((ext_vector_type(4))) float f32x4;

typedef const __attribute__((address_space(1))) void* gas_ptr;
typedef __attribute__((address_space(3))) void* las_ptr;

__device__ __forceinline__ uint32_t f2bf(float f) {
    union { float f; uint32_t u; } v; v.f = f;
    uint32_t u = v.u;
    return (u + 0x7FFFu + ((u >> 16) & 1u)) >> 16;   // RNE; inputs finite
}
__device__ __forceinline__ uint32_t pack2(float lo, float hi) {
    return f2bf(lo) | (f2bf(hi) << 16);
}

// ---- cast W into fragment-major bf16 Wb2f[cg][ks][lane][8]:
//      c = cg*16 + (lane&15), k = ks*32 + (lane>>4)*8 + e
//      (c<256 -> W[c][k] self half; c>=256 -> W[c-256][256+k] neighbor half)
// ---- and zero y2 row N (padding row for edge index -1)
__global__ __launch_bounds__(256) void cast_w2f_kernel(
    const float* __restrict__ W, ushort* __restrict__ Wb2f, ushort* __restrict__ y2)
{
    if (blockIdx.x < 64) {
        const int t = blockIdx.x * 256 + threadIdx.x;   // 0..16383
        const int cg   = t >> 9;          // 0..31
        const int ks   = (t >> 6) & 7;    // 0..7
        const int lane = t & 63;
        const int quad = lane >> 4, r16 = lane & 15;
        const int c = cg * 16 + r16;      // 0..511
        const int k = ks * 32 + quad * 8;
        const float* src = W + (size_t)(c & 255) * 512 + (c >> 8) * 256 + k;
        float4 v0 = ((const float4*)src)[0];
        float4 v1 = ((const float4*)src)[1];
        uint4 p = { pack2(v0.x, v0.y), pack2(v0.z, v0.w),
                    pack2(v1.x, v1.y), pack2(v1.z, v1.w) };
        *(uint4*)(Wb2f + (size_t)t * 8) = p;
    } else {
        if (threadIdx.x < 32) {
            uint4 z = {0u, 0u, 0u, 0u};
            *(uint4*)(y2 + (size_t)N_NODES_C * 256 + threadIdx.x * 8) = z;
        }
    }
}

// ---- Kernel A: 64-row tile. out[64,0:256] = x@W1^T + b (fp32 -> d_out),
// ----           y2[64,0:256] = x@W2^T (bf16 -> ws). 512 thr = 8 waves,
// ----           wave w owns 64 output cols x all four 16-row strips.
__global__ __launch_bounds__(512, 4) void gemm_xw_kernel(
    const float* __restrict__ x, const ushort* __restrict__ Wb2f,
    const float* __restrict__ bias, ushort* __restrict__ y2,
    float* __restrict__ out)
{
    __shared__ ushort sA[BM * LDS_A_STRIDE];   // 33,792 B

    const int tid = threadIdx.x;
    const int node0 = blockIdx.x * BM;

    // stage x tile -> bf16 LDS: 64 rows x 256 cols; 4 iters x 512 thr,
    // each thread converts 8 floats (32B load -> 16B LDS write)
    {
        #pragma unroll
        for (int it = 0; it < 4; ++it) {
            const int idx = it * 512 + tid;       // 8-float chunk id
            const int row = idx >> 5;             // 0..63
            const int c8  = idx & 31;             // chunk in row
            const int rg  = node0 + row;
            const float* src = x + (size_t)(rg < N_NODES_C ? rg : N_NODES_C - 1) * D_IN + c8 * 8;
            float4 v0 = ((const float4*)src)[0];
            float4 v1 = ((const float4*)src)[1];
            uint4 p = { pack2(v0.x, v0.y), pack2(v0.z, v0.w),
                        pack2(v1.x, v1.y), pack2(v1.z, v1.w) };
            *(uint4*)(sA + (size_t)row * LDS_A_STRIDE + c8 * 8) = p;
        }
    }
    __syncthreads();

    const int w = tid >> 6;              // 0..7 -> 64-col slice
    const int lane = tid & 63;
    const int quad = lane >> 4;
    const int r16  = lane & 15;

    f32x4 acc[4][4];                     // [row strip][col frag]
    #pragma unroll
    for (int s = 0; s < 4; ++s)
        #pragma unroll
        for (int j = 0; j < 4; ++j)
            acc[s][j] = (f32x4){0.f, 0.f, 0.f, 0.f};

    const ushort* ap = sA + (size_t)r16 * LDS_A_STRIDE + quad * 8;
    const ushort* bp = Wb2f + ((size_t)(w * 4) * 8 + 0) * 64 * 8 + lane * 8;

    #pragma unroll
    for (int ks = 0; ks < D_IN / 32; ++ks) {
        bf16x8 a0 = *(const bf16x8*)(ap + 0  * 16 * LDS_A_STRIDE + ks * 32);
        bf16x8 a1 = *(const bf16x8*)(ap + 1  * 16 * LDS_A_STRIDE + ks * 32);
        bf16x8 a2 = *(const bf16x8*)(ap + 2  * 16 * LDS_A_STRIDE + ks * 32);
        bf16x8 a3 = *(const bf16x8*)(ap + 3  * 16 * LDS_A_STRIDE + ks * 32);
        #pragma unroll
        for (int j = 0; j < 4; ++j) {
            // cg = w*4 + j; contiguous 1KB per wave-load
            bf16x8 b = *(const bf16x8*)(bp + ((size_t)j * 8 + ks) * 64 * 8);
            acc[0][j] = __builtin_amdgcn_mfma_f32_16x16x32_bf16(a0, b, acc[0][j], 0, 0, 0);
            acc[1][j] = __builtin_amdgcn_mfma_f32_16x16x32_bf16(a1, b, acc[1][j], 0, 0, 0);
            acc[2][j] = __builtin_amdgcn_mfma_f32_16x16x32_bf16(a2, b, acc[2][j], 0, 0, 0);
            acc[3][j] = __builtin_amdgcn_mfma_f32_16x16x32_bf16(a3, b, acc[3][j], 0, 0, 0);
        }
    }

    // D layout: col = lane&15 (-> c), row = quad*4 + reg
    if (w < 4) {   // cols 0..255: self term + bias -> out (fp32)
        #pragma unroll
        for (int j = 0; j < 4; ++j) {
            const int c = w * 64 + j * 16 + r16;
            const float bv = bias[c];
            #pragma unroll
            for (int s = 0; s < 4; ++s)
                #pragma unroll
                for (int r = 0; r < 4; ++r) {
                    const int row = node0 + s * 16 + quad * 4 + r;
                    if (row < N_NODES_C)
                        out[(size_t)row * D_OUT + c] = acc[s][j][r] + bv;
                }
        }
    } else {       // cols 256..511: neighbor-basis term -> y2 (bf16)
        #pragma unroll
        for (int j = 0; j < 4; ++j) {
            const int c2 = (w - 4) * 64 + j * 16 + r16;
            #pragma unroll
            for (int s = 0; s < 4; ++s)
                #pragma unroll
                for (int r = 0; r < 4; ++r) {
                    const int row = node0 + s * 16 + quad * 4 + r;
                    if (row < N_NODES_C)
                        y2[(size_t)row * 256 + c2] = (ushort)f2bf(acc[s][j][r]);
                }
        }
    }
}

// ---- Kernel B: wave handles NPW consecutive nodes with a double-buffered
// global_load_lds pipeline. Per iteration t: issue edge[t+2], DMAs for node
// t+1, out-row prefetch t+1; counted s_waitcnt vmcnt(11) (retires exactly
// node t's 8 DMAs + its yv in order); consume buf; store. Buffers alternate.
__global__ __launch_bounds__(128) void gather_add_kernel(
    const ushort* __restrict__ y2, const int* __restrict__ edge,
    float* __restrict__ out)
{
    __shared__ char sBuf[2 * 2 * 8192];                  // 2 waves x 2 bufs x 8KB

    const int wv   = threadIdx.x >> 6;                   // wave in block
    const int lane = threadIdx.x & 63;
    const int gw   = blockIdx.x * 2 + wv;                // global wave id
    const int base = gw * NPW;
    if (base >= N_NODES_C) return;
    const int count = min(NPW, N_NODES_C - base);

    char* bc = sBuf + wv * 16384;                        // current buffer
    char* bn = bc + 8192;                                // next buffer

    const char* yb = (const char*)y2;
    const uint32_t coff = (uint32_t)((lane & 31) * 16);  // 16B slot in 512B row
    const int l15  = lane & 15;
    const int half = lane >> 5;
    const int cw   = (lane & 31) * 8 + half * 4;         // out-row float offset

    // ---- prologue: edges for n0,n1; out-row n0; DMAs n0 -> bc ----
    int ecur = edge[(size_t)base * MAX_DEG + l15];
    const int t1p = (1 < count) ? 1 : count - 1;
    int enxt = edge[(size_t)(base + t1p) * MAX_DEG + l15];
    float4 yvcur = *(const float4*)(out + (size_t)base * D_OUT + cw);
    {
        const uint32_t om = (uint32_t)(ecur < 0 ? N_NODES_C : ecur) * 512u;
        #pragma unroll
        for (int k = 0; k < 8; ++k) {
            const uint32_t ro = (uint32_t)__shfl((int)om, 2 * k + half, 64);
            __builtin_amdgcn_global_load_lds((gas_ptr)(yb + (size_t)(ro + coff)),
                                             (las_ptr)(bc + k * 1024), 16, 0, 0);
        }
    }

    for (int t = 0; t < count; ++t) {
        // 1. edge prefetch for node t+2 (distance 2: older than next DMAs)
        const int t2 = (t + 2 < count) ? t + 2 : count - 1;
        const int e2 = edge[(size_t)(base + t2) * MAX_DEG + l15];
        // 2. DMAs for node t+1 into bn (enxt's load is older than node t's
        //    DMAs, so consuming it here does not drain them)
        {
            const uint32_t om = (uint32_t)(enxt < 0 ? N_NODES_C : enxt) * 512u;
            #pragma unroll
            for (int k = 0; k < 8; ++k) {
                const uint32_t ro = (uint32_t)__shfl((int)om, 2 * k + half, 64);
                __builtin_amdgcn_global_load_lds((gas_ptr)(yb + (size_t)(ro + coff)),
                                                 (las_ptr)(bn + k * 1024), 16, 0, 0);
            }
        }
        // 3. out-row prefetch for node t+1
        const int t1 = (t + 1 < count) ? t + 1 : count - 1;
        float4 yvn = *(const float4*)(out + (size_t)(base + t1) * D_OUT + cw);
        // 4. counted wait: newest 11 = {store t-1, e2, 8 DMA t+1, yv t+1}
        //    may remain; everything older (node t's 8 DMAs + yv) retired.
        asm volatile("s_waitcnt vmcnt(11)" ::: "memory");
        __builtin_amdgcn_sched_barrier(0);
        // 5. consume buf bc
        const int deg = (int)__popcll(__ballot(ecur >= 0) & 0xFFFFull);
        const float inv = 1.0f / (float)deg;
        float a[8];
        #pragma unroll
        for (int q = 0; q < 8; ++q) a[q] = 0.f;
        #pragma unroll
        for (int k = 0; k < 8; ++k) {
            uint4 g = *(const uint4*)(bc + k * 1024 + lane * 16);
            uint32_t u[4] = { g.x, g.y, g.z, g.w };
            #pragma unroll
            for (int q = 0; q < 4; ++q) {
                union { uint32_t ui; float f; } lo, hi;
                lo.ui = u[q] << 16;
                hi.ui = u[q] & 0xFFFF0000u;
                a[2*q]   += lo.f;
                a[2*q+1] += hi.f;
            }
        }
        #pragma unroll
        for (int q = 0; q < 8; ++q) a[q] += __shfl_xor(a[q], 32, 64);

        const int q0 = half * 4;
        float4 r;
        r.x = yvcur.x + inv * a[q0 + 0];
        r.y = yvcur.y + inv * a[q0 + 1];
        r.z = yvcur.z + inv * a[q0 + 2];
        r.w = yvcur.w + inv * a[q0 + 3];
        *(float4*)(out + (size_t)(base + t) * D_OUT + cw) = r;

        // rotate pipeline state
        ecur = enxt; enxt = e2; yvcur = yvn;
        char* tmp = bc; bc = bn; bn = tmp;
    }
}

// ---------------- fallback (small ws): fp32-gather path ----------------
#define D_K 512
#define LDS_STRIDE 520

__global__ __launch_bounds__(256) void cast_w_kernel(const float* __restrict__ W,
                                                     ushort* __restrict__ Wb) {
    int i = (blockIdx.x * 256 + threadIdx.x) * 4;
    float4 v = *(const float4*)(W + i);
    ushort4 p = { (ushort)f2bf(v.x), (ushort)f2bf(v.y),
                  (ushort)f2bf(v.z), (ushort)f2bf(v.w) };
    *(ushort4*)(Wb + i) = p;
}

__global__ __launch_bounds__(256) void sage_fp32_kernel(
    const float* __restrict__ x, const int* __restrict__ edge,
    const ushort* __restrict__ Wb, const float* __restrict__ bias,
    float* __restrict__ out)
{
    __shared__ ushort sH[32 * LDS_STRIDE];
    const int tid = threadIdx.x;
    const int node0 = blockIdx.x * 32;
    {
        const int m = tid >> 3, l = tid & 7;
        const int node = node0 + m;
        const float4* xrow = (const float4*)(x + (size_t)node * D_IN);
        ushort* dst = sH + m * LDS_STRIDE + l * 32;
        #pragma unroll
        for (int q = 0; q < 8; ++q) {
            float4 v = xrow[l * 8 + q];
            ushort4 p = { (ushort)f2bf(v.x), (ushort)f2bf(v.y),
                          (ushort)f2bf(v.z), (ushort)f2bf(v.w) };
            *(ushort4*)(dst + q * 4) = p;
        }
        float4 agg[8];
        #pragma unroll
        for (int q = 0; q < 8; ++q) agg[q] = make_float4(0.f,0.f,0.f,0.f);
        int deg = 0;
        for (int d = 0; d < MAX_DEG; ++d) {
            int nb = edge[(size_t)node * MAX_DEG + d];
            if (nb >= 0) {
                ++deg;
                const float4* nr = (const float4*)(x + (size_t)nb * D_IN);
                #pragma unroll
                for (int q = 0; q < 8; ++q) {
                    float4 t = nr[l * 8 + q];
                    agg[q].x += t.x; agg[q].y += t.y;
                    agg[q].z += t.z; agg[q].w += t.w;
                }
            }
        }
        const float inv = 1.0f / (float)deg;
        ushort* dst2 = sH + m * LDS_STRIDE + D_IN + l * 32;
        #pragma unroll
        for (int q = 0; q < 8; ++q) {
            ushort4 p = { (ushort)f2bf(agg[q].x*inv), (ushort)f2bf(agg[q].y*inv),
                          (ushort)f2bf(agg[q].z*inv), (ushort)f2bf(agg[q].w*inv) };
            *(ushort4*)(dst2 + q * 4) = p;
        }
    }
    __syncthreads();
    {
        const int wave = tid >> 6, lane = tid & 63;
        const int quad = lane >> 4, r16 = lane & 15;
        const int mt = wave & 1, nh = wave >> 1;
        f32x4 acc[8];
        #pragma unroll
        for (int j = 0; j < 8; ++j) {
            float bv = bias[(nh * 8 + j) * 16 + r16];
            acc[j] = (f32x4){bv, bv, bv, bv};
        }
        const ushort* arow = sH + (mt * 16 + r16) * LDS_STRIDE + quad * 8;
        #pragma unroll
        for (int ks = 0; ks < D_K / 32; ++ks) {
            bf16x8 a = *(const bf16x8*)(arow + ks * 32);
            #pragma unroll
            for (int j = 0; j < 8; ++j) {
                const int o = (nh * 8 + j) * 16 + r16;
                bf16x8 b = *(const bf16x8*)(Wb + (size_t)o * D_K + ks * 32 + quad * 8);
                acc[j] = __builtin_amdgcn_mfma_f32_16x16x32_bf16(a, b, acc[j], 0, 0, 0);
            }
        }
        #pragma unroll
        for (int j = 0; j < 8; ++j) {
            const int o = (nh * 8 + j) * 16 + r16;
            #pragma unroll
            for (int r = 0; r < 4; ++r) {
                const int row = node0 + mt * 16 + quad * 4 + r;
                out[(size_t)row * D_OUT + o] = acc[j][r];
            }
        }
    }
}

extern "C" void kernel_launch(void* const* d_in, const int* in_sizes, int n_in,
                              void* d_out, int out_size, void* d_ws, size_t ws_size,
                              hipStream_t stream) {
    const float* x    = (const float*)d_in[0];
    const int*   edge = (const int*)d_in[1];
    const float* W    = (const float*)d_in[2];
    const float* bias = (const float*)d_in[3];
    float* out = (float*)d_out;

    const size_t y2_bytes = (size_t)(N_NODES_C + 1) * 256 * 2;    // 51,200,512
    const size_t wb_bytes = (size_t)512 * 256 * 2;                // 262,144
    const int n = in_sizes[0] / D_IN;                             // 100000

    if (ws_size >= y2_bytes + wb_bytes) {
        ushort* y2   = (ushort*)d_ws;
        ushort* Wb2f = (ushort*)((char*)d_ws + y2_bytes);
        cast_w2f_kernel<<<65, 256, 0, stream>>>(W, Wb2f, y2);
        gemm_xw_kernel<<<(n + BM - 1) / BM, 512, 0, stream>>>(x, Wb2f, bias, y2, out);
        const int nwaves = (n + NPW - 1) / NPW;                   // 6250
        gather_add_kernel<<<(nwaves + 1) / 2, 128, 0, stream>>>(y2, edge, out);
    } else {
        ushort* Wb = (ushort*)d_ws;     // 256 KB
        cast_w_kernel<<<(D_OUT * D_K) / 1024, 256, 0, stream>>>(W, Wb);
        sage_fp32_kernel<<<n / 32, 256, 0, stream>>>(x, edge, Wb, bias, out);
    }
}

// Round 9
// 373.671 us; speedup vs baseline: 1.0287x; 1.0287x over previous
//
#include <hip/hip_runtime.h>
#include <stdint.h>

// SAGEConv via linearity: out = x@W1^T + b + mean_neigh(x)@W2^T
//                             = [x@W1^T + b] + mean_d( (x@W2^T)[e_d] )
// N=100000, MAX_DEG=16, D_IN=256, D_OUT=256
//
// R12: gather BW is pinned ~3.9 TB/s across 3 structures -> service floor;
// revert to R10's best gather and cut bytes instead: self-term stored bf16
// in out-row first half (saves 49MB write + 49MB read). GEMM had the same
// latency-collapsed staging as the old gather (VGPR=36, MfmaUtil 6.6%) ->
// stage x fp32 via global_load_lds (8 DMA/wave, no dest regs), XOR-swizzled
// per-lane global source (slot = chunk ^ (row&7)), bf16 convert at consume.

#define MAX_DEG 16
#define D_IN 256
#define D_OUT 256
#define N_NODES_C 100000
#define BM 64

typedef __attribute__((ext_vector_type(8))) short bf16x8;   // 8 bf16 = 4 VGPRs
typedef __attribute__((ext_vector_type(4))) float f32x4;

typedef const __attribute__((address_space(1))) void* gas_ptr;
typedef __attribute__((address_space(3))) void* las_ptr;

__device__ __forceinline__ uint32_t f2bf(float f) {
    union { float f; uint32_t u; } v; v.f = f;
    uint32_t u = v.u;
    return (u + 0x7FFFu + ((u >> 16) & 1u)) >> 16;   // RNE; inputs finite
}
__device__ __forceinline__ uint32_t pack2(float lo, float hi) {
    return f2bf(lo) | (f2bf(hi) << 16);
}

// ---- cast W into fragment-major bf16 Wb2f[cg][ks][lane][8]:
//      c = cg*16 + (lane&15), k = ks*32 + (lane>>4)*8 + e
//      (c<256 -> W[c][k] self half; c>=256 -> W[c-256][256+k] neighbor half)
// ---- and zero y2 row N (padding row for edge index -1)
__global__ __launch_bounds__(256) void cast_w2f_kernel(
    const float* __restrict__ W, ushort* __restrict__ Wb2f, ushort* __restrict__ y2)
{
    if (blockIdx.x < 64) {
        const int t = blockIdx.x * 256 + threadIdx.x;   // 0..16383
        const int cg   = t >> 9;          // 0..31
        const int ks   = (t >> 6) & 7;    // 0..7
        const int lane = t & 63;
        const int quad = lane >> 4, r16 = lane & 15;
        const int c = cg * 16 + r16;      // 0..511
        const int k = ks * 32 + quad * 8;
        const float* src = W + (size_t)(c & 255) * 512 + (c >> 8) * 256 + k;
        float4 v0 = ((const float4*)src)[0];
        float4 v1 = ((const float4*)src)[1];
        uint4 p = { pack2(v0.x, v0.y), pack2(v0.z, v0.w),
                    pack2(v1.x, v1.y), pack2(v1.z, v1.w) };
        *(uint4*)(Wb2f + (size_t)t * 8) = p;
    } else {
        if (threadIdx.x < 32) {
            uint4 z = {0u, 0u, 0u, 0u};
            *(uint4*)(y2 + (size_t)N_NODES_C * 256 + threadIdx.x * 8) = z;
        }
    }
}

// ---- Kernel A: 64-row tile. y1[64] = bf16(x@W1^T + b) -> out-row first
// ---- 512B; y2[64] = bf16(x@W2^T) -> ws. x staged fp32 via global_load_lds
// ---- with 16B-chunk XOR swizzle; bf16 conversion at fragment load.
__global__ __launch_bounds__(512, 4) void gemm_xw_kernel(
    const float* __restrict__ x, const ushort* __restrict__ Wb2f,
    const float* __restrict__ bias, ushort* __restrict__ y2,
    float* __restrict__ out)
{
    __shared__ float sX[BM * 256];       // 65,536 B; row r = 64 chunks of 16B,
                                         // chunk c stored at slot c ^ (r&7)

    const int tid = threadIdx.x;
    const int node0 = blockIdx.x * BM;
    const int w = tid >> 6;              // 0..7
    const int lane = tid & 63;

    // stage: wave w DMAs rows w*8+it (1KB each = 64 lanes x 16B);
    // lane fetches global chunk (lane ^ it) so LDS slot l holds chunk l^it
    #pragma unroll
    for (int it = 0; it < 8; ++it) {
        const int R = w * 8 + it;        // R & 7 == it
        const int rg = node0 + R;
        const float* rowp = x + (size_t)(rg < N_NODES_C ? rg : N_NODES_C - 1) * D_IN;
        const char* gsrc = (const char*)rowp + ((lane ^ it) << 4);
        __builtin_amdgcn_global_load_lds((gas_ptr)gsrc,
            (las_ptr)((char*)sX + (size_t)R * 1024), 16, 0, 0);
    }
    __syncthreads();

    const int quad = lane >> 4;
    const int r16  = lane & 15;
    const int x7   = r16 & 7;

    f32x4 acc[4][4];                     // [row strip][col frag]
    #pragma unroll
    for (int s = 0; s < 4; ++s)
        #pragma unroll
        for (int j = 0; j < 4; ++j)
            acc[s][j] = (f32x4){0.f, 0.f, 0.f, 0.f};

    const char* aB[4];
    #pragma unroll
    for (int s = 0; s < 4; ++s)
        aB[s] = (const char*)sX + (size_t)(s * 16 + r16) * 1024;
    const ushort* bp = Wb2f + ((size_t)(w * 4) * 8 + 0) * 64 * 8 + lane * 8;

    #pragma unroll
    for (int ks = 0; ks < D_IN / 32; ++ks) {
        const int ch = ks * 8 + quad * 2;         // 16B-chunk index (even)
        bf16x8 afr[4];
        #pragma unroll
        for (int s = 0; s < 4; ++s) {
            f32x4 lo = *(const f32x4*)(aB[s] + ((ch ^ x7) << 4));
            f32x4 hi = *(const f32x4*)(aB[s] + (((ch + 1) ^ x7) << 4));
            union { uint32_t u[4]; bf16x8 v; } cv;
            cv.u[0] = pack2(lo.x, lo.y);
            cv.u[1] = pack2(lo.z, lo.w);
            cv.u[2] = pack2(hi.x, hi.y);
            cv.u[3] = pack2(hi.z, hi.w);
            afr[s] = cv.v;
        }
        #pragma unroll
        for (int j = 0; j < 4; ++j) {
            // cg = w*4 + j; contiguous 1KB per wave-load (L2-resident W)
            bf16x8 b = *(const bf16x8*)(bp + ((size_t)j * 8 + ks) * 64 * 8);
            acc[0][j] = __builtin_amdgcn_mfma_f32_16x16x32_bf16(afr[0], b, acc[0][j], 0, 0, 0);
            acc[1][j] = __builtin_amdgcn_mfma_f32_16x16x32_bf16(afr[1], b, acc[1][j], 0, 0, 0);
            acc[2][j] = __builtin_amdgcn_mfma_f32_16x16x32_bf16(afr[2], b, acc[2][j], 0, 0, 0);
            acc[3][j] = __builtin_amdgcn_mfma_f32_16x16x32_bf16(afr[3], b, acc[3][j], 0, 0, 0);
        }
    }

    // D layout: col = lane&15 (-> c), row = quad*4 + reg
    if (w < 4) {   // cols 0..255: self term + bias -> bf16 y1 in out-row head
        #pragma unroll
        for (int j = 0; j < 4; ++j) {
            const int c = w * 64 + j * 16 + r16;
            const float bv = bias[c];
            #pragma unroll
            for (int s = 0; s < 4; ++s)
                #pragma unroll
                for (int r = 0; r < 4; ++r) {
                    const int row = node0 + s * 16 + quad * 4 + r;
                    if (row < N_NODES_C)
                        ((ushort*)(out + (size_t)row * D_OUT))[c] =
                            (ushort)f2bf(acc[s][j][r] + bv);
                }
        }
    } else {       // cols 256..511: neighbor-basis term -> y2 (bf16)
        #pragma unroll
        for (int j = 0; j < 4; ++j) {
            const int c2 = (w - 4) * 64 + j * 16 + r16;
            #pragma unroll
            for (int s = 0; s < 4; ++s)
                #pragma unroll
                for (int r = 0; r < 4; ++r) {
                    const int row = node0 + s * 16 + quad * 4 + r;
                    if (row < N_NODES_C)
                        y2[(size_t)row * 256 + c2] = (ushort)f2bf(acc[s][j][r]);
                }
        }
    }
}

// ---- Kernel B (R10 form): one node per wave. out[i] = y1[i] + inv*sum y2[e_d].
// 8 async global_load_lds row-pair copies (1KB each) into a private 8KB LDS
// slice; one vmcnt(0); conflict-free readback. y1 read as bf16 (8B/lane)
// from the out-row head; full fp32 row written back.
__global__ __launch_bounds__(256, 5) void gather_add_kernel(
    const ushort* __restrict__ y2, const int* __restrict__ edge,
    float* __restrict__ out)
{
    __shared__ char sBuf[4 * 8 * 1024];                  // 32 KB: 4 waves x 8KB

    const int w4   = threadIdx.x >> 6;                   // wave in block
    const int lane = threadIdx.x & 63;
    const int i = blockIdx.x * 4 + w4;                   // node, 0..99999

    const int e = edge[(size_t)i * MAX_DEG + (lane & 15)];
    const unsigned long long vm = __ballot(e >= 0);
    const int deg = (int)__popcll(vm & 0xFFFFull);       // >= 1
    const float inv = 1.0f / (float)deg;

    const uint32_t off_me = (uint32_t)(e < 0 ? N_NODES_C : e) * 512u;  // row bytes
    const char* yb = (const char*)y2;
    const uint32_t coff = (uint32_t)((lane & 31) * 16);  // 16B slot within 512B row
    const int half = lane >> 5;

    // y1 prefetch: 4 bf16 (8B) covering this lane's 4 output floats
    const int cw = (lane & 31) * 8 + half * 4;           // float col base
    float* op = out + (size_t)i * D_OUT + cw;
    const uint2 y1p = *(const uint2*)((const char*)(out + (size_t)i * D_OUT) + cw * 2);

    // issue 8 async row-pair copies: chunk k = rows e_{2k} (lanes 0..31)
    // and e_{2k+1} (lanes 32..63); LDS dest = wavebase + k*1024 + lane*16
    char* lw = sBuf + (size_t)w4 * 8192;
    #pragma unroll
    for (int k = 0; k < 8; ++k) {
        const uint32_t ro = (uint32_t)__shfl((int)off_me, 2 * k + half, 64);
        const char* gsrc = yb + (size_t)(ro + coff);
        __builtin_amdgcn_global_load_lds((gas_ptr)gsrc, (las_ptr)(lw + k * 1024),
                                         16, 0, 0);
    }
    asm volatile("s_waitcnt vmcnt(0)" ::: "memory");
    __builtin_amdgcn_sched_barrier(0);

    float a[8];
    #pragma unroll
    for (int q = 0; q < 8; ++q) a[q] = 0.f;
    #pragma unroll
    for (int k = 0; k < 8; ++k) {
        uint4 g = *(const uint4*)(lw + k * 1024 + lane * 16);
        uint32_t u[4] = { g.x, g.y, g.z, g.w };
        #pragma unroll
        for (int q = 0; q < 4; ++q) {
            union { uint32_t ui; float f; } lo, hi;
            lo.ui = u[q] << 16;
            hi.ui = u[q] & 0xFFFF0000u;
            a[2*q]   += lo.f;
            a[2*q+1] += hi.f;
        }
    }
    // combine even-d half (lanes<32) with odd-d half (lanes>=32)
    #pragma unroll
    for (int q = 0; q < 8; ++q) a[q] += __shfl_xor(a[q], 32, 64);

    // unpack y1 bf16 -> fp32 and finalize: out = y1 + inv * sum
    const int q0 = half * 4;
    union { uint32_t ui; float f; } c0, c1, c2, c3;
    c0.ui = y1p.x << 16; c1.ui = y1p.x & 0xFFFF0000u;
    c2.ui = y1p.y << 16; c3.ui = y1p.y & 0xFFFF0000u;
    float4 r;
    r.x = c0.f + inv * a[q0 + 0];
    r.y = c1.f + inv * a[q0 + 1];
    r.z = c2.f + inv * a[q0 + 2];
    r.w = c3.f + inv * a[q0 + 3];
    *(float4*)op = r;
}

// ---------------- fallback (small ws): fp32-gather path ----------------
#define D_K 512
#define LDS_STRIDE 520

__global__ __launch_bounds__(256) void cast_w_kernel(const float* __restrict__ W,
                                                     ushort* __restrict__ Wb) {
    int i = (blockIdx.x * 256 + threadIdx.x) * 4;
    float4 v = *(const float4*)(W + i);
    ushort4 p = { (ushort)f2bf(v.x), (ushort)f2bf(v.y),
                  (ushort)f2bf(v.z), (ushort)f2bf(v.w) };
    *(ushort4*)(Wb + i) = p;
}

__global__ __launch_bounds__(256) void sage_fp32_kernel(
    const float* __restrict__ x, const int* __restrict__ edge,
    const ushort* __restrict__ Wb, const float* __restrict__ bias,
    float* __restrict__ out)
{
    __shared__ ushort sH[32 * LDS_STRIDE];
    const int tid = threadIdx.x;
    const int node0 = blockIdx.x * 32;
    {
        const int m = tid >> 3, l = tid & 7;
        const int node = node0 + m;
        const float4* xrow = (const float4*)(x + (size_t)node * D_IN);
        ushort* dst = sH + m * LDS_STRIDE + l * 32;
        #pragma unroll
        for (int q = 0; q < 8; ++q) {
            float4 v = xrow[l * 8 + q];
            ushort4 p = { (ushort)f2bf(v.x), (ushort)f2bf(v.y),
                          (ushort)f2bf(v.z), (ushort)f2bf(v.w) };
            *(ushort4*)(dst + q * 4) = p;
        }
        float4 agg[8];
        #pragma unroll
        for (int q = 0; q < 8; ++q) agg[q] = make_float4(0.f,0.f,0.f,0.f);
        int deg = 0;
        for (int d = 0; d < MAX_DEG; ++d) {
            int nb = edge[(size_t)node * MAX_DEG + d];
            if (nb >= 0) {
                ++deg;
                const float4* nr = (const float4*)(x + (size_t)nb * D_IN);
                #pragma unroll
                for (int q = 0; q < 8; ++q) {
                    float4 t = nr[l * 8 + q];
                    agg[q].x += t.x; agg[q].y += t.y;
                    agg[q].z += t.z; agg[q].w += t.w;
                }
            }
        }
        const float inv = 1.0f / (float)deg;
        ushort* dst2 = sH + m * LDS_STRIDE + D_IN + l * 32;
        #pragma unroll
        for (int q = 0; q < 8; ++q) {
            ushort4 p = { (ushort)f2bf(agg[q].x*inv), (ushort)f2bf(agg[q].y*inv),
                          (ushort)f2bf(agg[q].z*inv), (ushort)f2bf(agg[q].w*inv) };
            *(ushort4*)(dst2 + q * 4) = p;
        }
    }
    __syncthreads();
    {
        const int wave = tid >> 6, lane = tid & 63;
        const int quad = lane >> 4, r16 = lane & 15;
        const int mt = wave & 1, nh = wave >> 1;
        f32x4 acc[8];
        #pragma unroll
        for (int j = 0; j < 8; ++j) {
            float bv = bias[(nh * 8 + j) * 16 + r16];
            acc[j] = (f32x4){bv, bv, bv, bv};
        }
        const ushort* arow = sH + (mt * 16 + r16) * LDS_STRIDE + quad * 8;
        #pragma unroll
        for (int ks = 0; ks < D_K / 32; ++ks) {
            bf16x8 a = *(const bf16x8*)(arow + ks * 32);
            #pragma unroll
            for (int j = 0; j < 8; ++j) {
                const int o = (nh * 8 + j) * 16 + r16;
                bf16x8 b = *(const bf16x8*)(Wb + (size_t)o * D_K + ks * 32 + quad * 8);
                acc[j] = __builtin_amdgcn_mfma_f32_16x16x32_bf16(a, b, acc[j], 0, 0, 0);
            }
        }
        #pragma unroll
        for (int j = 0; j < 8; ++j) {
            const int o = (nh * 8 + j) * 16 + r16;
            #pragma unroll
            for (int r = 0; r < 4; ++r) {
                const int row = node0 + mt * 16 + quad * 4 + r;
                out[(size_t)row * D_OUT + o] = acc[j][r];
            }
        }
    }
}

extern "C" void kernel_launch(void* const* d_in, const int* in_sizes, int n_in,
                              void* d_out, int out_size, void* d_ws, size_t ws_size,
                              hipStream_t stream) {
    const float* x    = (const float*)d_in[0];
    const int*   edge = (const int*)d_in[1];
    const float* W    = (const float*)d_in[2];
    const float* bias = (const float*)d_in[3];
    float* out = (float*)d_out;

    const size_t y2_bytes = (size_t)(N_NODES_C + 1) * 256 * 2;    // 51,200,512
    const size_t wb_bytes = (size_t)512 * 256 * 2;                // 262,144
    const int n = in_sizes[0] / D_IN;                             // 100000

    if (ws_size >= y2_bytes + wb_bytes) {
        ushort* y2   = (ushort*)d_ws;
        ushort* Wb2f = (ushort*)((char*)d_ws + y2_bytes);
        cast_w2f_kernel<<<65, 256, 0, stream>>>(W, Wb2f, y2);
        gemm_xw_kernel<<<(n + BM - 1) / BM, 512, 0, stream>>>(x, Wb2f, bias, y2, out);
        gather_add_kernel<<<n / 4, 256, 0, stream>>>(y2, edge, out);
    } else {
        ushort* Wb = (ushort*)d_ws;     // 256 KB
        cast_w_kernel<<<(D_OUT * D_K) / 1024, 256, 0, stream>>>(W, Wb);
        sage_fp32_kernel<<<n / 32, 256, 0, stream>>>(x, edge, Wb, bias, out);
    }
}

// Round 10
// 361.382 us; speedup vs baseline: 1.0637x; 1.0340x over previous
//
#include <hip/hip_runtime.h>
#include <stdint.h>

// SAGEConv via linearity: out = x@W1^T + b + mean_neigh(x)@W2^T
//                             = [x@W1^T + b] + mean_d( (x@W2^T)[e_d] )
// N=100000, MAX_DEG=16, D_IN=256, D_OUT=256
//
// R13: GEMM stuck ~125us (R5 counters: VGPR=36 -> serialized B loads;
// 2-4B scattered epilogue stores -> L2 RMW amplification). Fixes:
// (1) B-frag double-buffer in regs, one scalar-operand pin per ks (R9-style
//     asm, proven compilable) -> 4x1KB L2 loads in flight per wave;
// (2) epilogue via LDS (reuse 64KB stage buffer, XOR-swizzled slots):
//     acc -> bf16 LDS -> linear 16B/lane coalesced global stores.
// Gather: unchanged from R12 (129.7us, random-row service floor).

#define MAX_DEG 16
#define D_IN 256
#define D_OUT 256
#define N_NODES_C 100000
#define BM 64

typedef __attribute__((ext_vector_type(8))) short bf16x8;   // 8 bf16 = 4 VGPRs
typedef __attribute__((ext_vector_type(4))) float f32x4;

typedef const __attribute__((address_space(1))) void* gas_ptr;
typedef __attribute__((address_space(3))) void* las_ptr;

__device__ __forceinline__ uint32_t f2bf(float f) {
    union { float f; uint32_t u; } v; v.f = f;
    uint32_t u = v.u;
    return (u + 0x7FFFu + ((u >> 16) & 1u)) >> 16;   // RNE; inputs finite
}
__device__ __forceinline__ uint32_t pack2(float lo, float hi) {
    return f2bf(lo) | (f2bf(hi) << 16);
}

// ---- cast W into fragment-major bf16 Wb2f[cg][ks][lane][8]:
//      c = cg*16 + (lane&15), k = ks*32 + (lane>>4)*8 + e
//      (c<256 -> W[c][k] self half; c>=256 -> W[c-256][256+k] neighbor half)
// ---- and zero y2 row N (padding row for edge index -1)
__global__ __launch_bounds__(256) void cast_w2f_kernel(
    const float* __restrict__ W, ushort* __restrict__ Wb2f, ushort* __restrict__ y2)
{
    if (blockIdx.x < 64) {
        const int t = blockIdx.x * 256 + threadIdx.x;   // 0..16383
        const int cg   = t >> 9;          // 0..31
        const int ks   = (t >> 6) & 7;    // 0..7
        const int lane = t & 63;
        const int quad = lane >> 4, r16 = lane & 15;
        const int c = cg * 16 + r16;      // 0..511
        const int k = ks * 32 + quad * 8;
        const float* src = W + (size_t)(c & 255) * 512 + (c >> 8) * 256 + k;
        float4 v0 = ((const float4*)src)[0];
        float4 v1 = ((const float4*)src)[1];
        uint4 p = { pack2(v0.x, v0.y), pack2(v0.z, v0.w),
                    pack2(v1.x, v1.y), pack2(v1.z, v1.w) };
        *(uint4*)(Wb2f + (size_t)t * 8) = p;
    } else {
        if (threadIdx.x < 32) {
            uint4 z = {0u, 0u, 0u, 0u};
            *(uint4*)(y2 + (size_t)N_NODES_C * 256 + threadIdx.x * 8) = z;
        }
    }
}

// pin 4 B-frags (as 16 scalar u32) live at one point
#define PINB4(b0, b1, b2, b3) do {                                          \
    const uint4& u0 = *(const uint4*)&(b0);                                 \
    const uint4& u1 = *(const uint4*)&(b1);                                 \
    const uint4& u2 = *(const uint4*)&(b2);                                 \
    const uint4& u3 = *(const uint4*)&(b3);                                 \
    asm volatile("" :: "v"(u0.x), "v"(u0.y), "v"(u0.z), "v"(u0.w),          \
                       "v"(u1.x), "v"(u1.y), "v"(u1.z), "v"(u1.w),          \
                       "v"(u2.x), "v"(u2.y), "v"(u2.z), "v"(u2.w),          \
                       "v"(u3.x), "v"(u3.y), "v"(u3.z), "v"(u3.w));         \
} while (0)

// ---- Kernel A: 64-row tile. y1[64] = bf16(x@W1^T + b) -> out-row first
// ---- 512B; y2[64] = bf16(x@W2^T) -> ws. x staged fp32 via global_load_lds
// ---- (XOR-swizzled source); B double-buffered in regs; epilogue via LDS.
__global__ __launch_bounds__(512, 2) void gemm_xw_kernel(
    const float* __restrict__ x, const ushort* __restrict__ Wb2f,
    const float* __restrict__ bias, ushort* __restrict__ y2,
    float* __restrict__ out)
{
    __shared__ float sX[BM * 256];       // 65,536 B; stage + epilogue reuse

    const int tid = threadIdx.x;
    const int node0 = blockIdx.x * BM;
    const int w = tid >> 6;              // 0..7
    const int lane = tid & 63;

    // stage: wave w DMAs rows w*8+it (1KB each = 64 lanes x 16B);
    // lane fetches global chunk (lane ^ it) so LDS slot l holds chunk l^it
    #pragma unroll
    for (int it = 0; it < 8; ++it) {
        const int R = w * 8 + it;        // R & 7 == it
        const int rg = node0 + R;
        const float* rowp = x + (size_t)(rg < N_NODES_C ? rg : N_NODES_C - 1) * D_IN;
        const char* gsrc = (const char*)rowp + ((lane ^ it) << 4);
        __builtin_amdgcn_global_load_lds((gas_ptr)gsrc,
            (las_ptr)((char*)sX + (size_t)R * 1024), 16, 0, 0);
    }

    const int quad = lane >> 4;
    const int r16  = lane & 15;
    const int x7   = r16 & 7;
    const int cb   = (w & 3) * 64;

    // bias for this wave's 4 col-frags (used only if w<4)
    float bv[4];
    #pragma unroll
    for (int j = 0; j < 4; ++j)
        bv[j] = bias[cb + j * 16 + r16];

    __syncthreads();

    f32x4 acc[4][4];                     // [row strip][col frag]
    #pragma unroll
    for (int s = 0; s < 4; ++s)
        #pragma unroll
        for (int j = 0; j < 4; ++j)
            acc[s][j] = (f32x4){0.f, 0.f, 0.f, 0.f};

    const char* aB[4];
    #pragma unroll
    for (int s = 0; s < 4; ++s)
        aB[s] = (const char*)sX + (size_t)(s * 16 + r16) * 1024;
    const ushort* bp = Wb2f + ((size_t)(w * 4) * 8 + 0) * 64 * 8 + lane * 8;

    // B double-buffer: load ks=0, pin; per ks load ks+1, pin, MFMA current
    bf16x8 bcur[4], bnxt[4];
    #pragma unroll
    for (int j = 0; j < 4; ++j)
        bcur[j] = *(const bf16x8*)(bp + ((size_t)j * 8 + 0) * 64 * 8);
    PINB4(bcur[0], bcur[1], bcur[2], bcur[3]);

    #pragma unroll
    for (int ks = 0; ks < D_IN / 32; ++ks) {
        if (ks < D_IN / 32 - 1) {
            #pragma unroll
            for (int j = 0; j < 4; ++j)
                bnxt[j] = *(const bf16x8*)(bp + ((size_t)j * 8 + ks + 1) * 64 * 8);
            PINB4(bnxt[0], bnxt[1], bnxt[2], bnxt[3]);
        }
        const int ch = ks * 8 + quad * 2;         // 16B-chunk index (even)
        bf16x8 afr[4];
        #pragma unroll
        for (int s = 0; s < 4; ++s) {
            f32x4 lo = *(const f32x4*)(aB[s] + ((ch ^ x7) << 4));
            f32x4 hi = *(const f32x4*)(aB[s] + (((ch + 1) ^ x7) << 4));
            union { uint32_t u[4]; bf16x8 v; } cv;
            cv.u[0] = pack2(lo.x, lo.y);
            cv.u[1] = pack2(lo.z, lo.w);
            cv.u[2] = pack2(hi.x, hi.y);
            cv.u[3] = pack2(hi.z, hi.w);
            afr[s] = cv.v;
        }
        #pragma unroll
        for (int j = 0; j < 4; ++j) {
            acc[0][j] = __builtin_amdgcn_mfma_f32_16x16x32_bf16(afr[0], bcur[j], acc[0][j], 0, 0, 0);
            acc[1][j] = __builtin_amdgcn_mfma_f32_16x16x32_bf16(afr[1], bcur[j], acc[1][j], 0, 0, 0);
            acc[2][j] = __builtin_amdgcn_mfma_f32_16x16x32_bf16(afr[2], bcur[j], acc[2][j], 0, 0, 0);
            acc[3][j] = __builtin_amdgcn_mfma_f32_16x16x32_bf16(afr[3], bcur[j], acc[3][j], 0, 0, 0);
        }
        #pragma unroll
        for (int j = 0; j < 4; ++j) bcur[j] = bnxt[j];
    }

    // ---- epilogue: acc -> bf16 LDS (XOR-swizzled 16B slots), then linear
    // ---- coalesced copy-out. region 0 = y1 (self+bias), region 1 = y2.
    __syncthreads();                     // all A reads done; sX reusable
    {
        ushort* sE = (ushort*)sX;
        const int reg_ = (w < 4) ? 0 : 1;
        #pragma unroll
        for (int j = 0; j < 4; ++j) {
            const int c = cb + j * 16 + r16;
            #pragma unroll
            for (int s = 0; s < 4; ++s)
                #pragma unroll
                for (int r = 0; r < 4; ++r) {
                    const int row = s * 16 + quad * 4 + r;
                    const float v = acc[s][j][r] + (reg_ ? 0.f : bv[j]);
                    // ushort addr: slot = (c>>3) ^ (row&7); 8 ushorts/slot
                    const int a = reg_ * 16384 + row * 256 +
                                  ((((c >> 3) ^ (row & 7)) << 3) | (c & 7));
                    sE[a] = (ushort)f2bf(v);
                }
        }
    }
    __syncthreads();
    {
        const ushort* sE = (const ushort*)sX;
        #pragma unroll
        for (int t = 0; t < 8; ++t) {
            const int idx = t * 512 + tid;        // 0..4095 16B-chunks
            const int reg_ = idx >> 11;           // 0: y1, 1: y2
            const int rowch = idx & 2047;
            const int row = rowch >> 5;           // 0..63
            const int ch  = rowch & 31;           // 16B chunk in row
            const int rg = node0 + row;
            if (rg < N_NODES_C) {
                const uint4 v = *(const uint4*)(sE + reg_ * 16384 + row * 256 +
                                                ((ch ^ (row & 7)) << 3));
                char* dst = reg_ == 0
                    ? (char*)(out + (size_t)rg * D_OUT) + ch * 16
                    : (char*)y2 + (size_t)rg * 512 + ch * 16;
                *(uint4*)dst = v;
            }
        }
    }
}

// ---- Kernel B (R12 form, unchanged): one node per wave.
// out[i] = y1[i] + inv*sum y2[e_d]. 8 async global_load_lds row-pair copies
// into a private 8KB LDS slice; one vmcnt(0); conflict-free readback.
__global__ __launch_bounds__(256, 5) void gather_add_kernel(
    const ushort* __restrict__ y2, const int* __restrict__ edge,
    float* __restrict__ out)
{
    __shared__ char sBuf[4 * 8 * 1024];                  // 32 KB: 4 waves x 8KB

    const int w4   = threadIdx.x >> 6;                   // wave in block
    const int lane = threadIdx.x & 63;
    const int i = blockIdx.x * 4 + w4;                   // node, 0..99999

    const int e = edge[(size_t)i * MAX_DEG + (lane & 15)];
    const unsigned long long vm = __ballot(e >= 0);
    const int deg = (int)__popcll(vm & 0xFFFFull);       // >= 1
    const float inv = 1.0f / (float)deg;

    const uint32_t off_me = (uint32_t)(e < 0 ? N_NODES_C : e) * 512u;  // row bytes
    const char* yb = (const char*)y2;
    const uint32_t coff = (uint32_t)((lane & 31) * 16);  // 16B slot within 512B row
    const int half = lane >> 5;

    // y1 prefetch: 4 bf16 (8B) covering this lane's 4 output floats
    const int cw = (lane & 31) * 8 + half * 4;           // float col base
    float* op = out + (size_t)i * D_OUT + cw;
    const uint2 y1p = *(const uint2*)((const char*)(out + (size_t)i * D_OUT) + cw * 2);

    // issue 8 async row-pair copies: chunk k = rows e_{2k} (lanes 0..31)
    // and e_{2k+1} (lanes 32..63); LDS dest = wavebase + k*1024 + lane*16
    char* lw = sBuf + (size_t)w4 * 8192;
    #pragma unroll
    for (int k = 0; k < 8; ++k) {
        const uint32_t ro = (uint32_t)__shfl((int)off_me, 2 * k + half, 64);
        const char* gsrc = yb + (size_t)(ro + coff);
        __builtin_amdgcn_global_load_lds((gas_ptr)gsrc, (las_ptr)(lw + k * 1024),
                                         16, 0, 0);
    }
    asm volatile("s_waitcnt vmcnt(0)" ::: "memory");
    __builtin_amdgcn_sched_barrier(0);

    float a[8];
    #pragma unroll
    for (int q = 0; q < 8; ++q) a[q] = 0.f;
    #pragma unroll
    for (int k = 0; k < 8; ++k) {
        uint4 g = *(const uint4*)(lw + k * 1024 + lane * 16);
        uint32_t u[4] = { g.x, g.y, g.z, g.w };
        #pragma unroll
        for (int q = 0; q < 4; ++q) {
            union { uint32_t ui; float f; } lo, hi;
            lo.ui = u[q] << 16;
            hi.ui = u[q] & 0xFFFF0000u;
            a[2*q]   += lo.f;
            a[2*q+1] += hi.f;
        }
    }
    // combine even-d half (lanes<32) with odd-d half (lanes>=32)
    #pragma unroll
    for (int q = 0; q < 8; ++q) a[q] += __shfl_xor(a[q], 32, 64);

    // unpack y1 bf16 -> fp32 and finalize: out = y1 + inv * sum
    const int q0 = half * 4;
    union { uint32_t ui; float f; } c0, c1, c2, c3;
    c0.ui = y1p.x << 16; c1.ui = y1p.x & 0xFFFF0000u;
    c2.ui = y1p.y << 16; c3.ui = y1p.y & 0xFFFF0000u;
    float4 r;
    r.x = c0.f + inv * a[q0 + 0];
    r.y = c1.f + inv * a[q0 + 1];
    r.z = c2.f + inv * a[q0 + 2];
    r.w = c3.f + inv * a[q0 + 3];
    *(float4*)op = r;
}

// ---------------- fallback (small ws): fp32-gather path ----------------
#define D_K 512
#define LDS_STRIDE 520

__global__ __launch_bounds__(256) void cast_w_kernel(const float* __restrict__ W,
                                                     ushort* __restrict__ Wb) {
    int i = (blockIdx.x * 256 + threadIdx.x) * 4;
    float4 v = *(const float4*)(W + i);
    ushort4 p = { (ushort)f2bf(v.x), (ushort)f2bf(v.y),
                  (ushort)f2bf(v.z), (ushort)f2bf(v.w) };
    *(ushort4*)(Wb + i) = p;
}

__global__ __launch_bounds__(256) void sage_fp32_kernel(
    const float* __restrict__ x, const int* __restrict__ edge,
    const ushort* __restrict__ Wb, const float* __restrict__ bias,
    float* __restrict__ out)
{
    __shared__ ushort sH[32 * LDS_STRIDE];
    const int tid = threadIdx.x;
    const int node0 = blockIdx.x * 32;
    {
        const int m = tid >> 3, l = tid & 7;
        const int node = node0 + m;
        const float4* xrow = (const float4*)(x + (size_t)node * D_IN);
        ushort* dst = sH + m * LDS_STRIDE + l * 32;
        #pragma unroll
        for (int q = 0; q < 8; ++q) {
            float4 v = xrow[l * 8 + q];
            ushort4 p = { (ushort)f2bf(v.x), (ushort)f2bf(v.y),
                          (ushort)f2bf(v.z), (ushort)f2bf(v.w) };
            *(ushort4*)(dst + q * 4) = p;
        }
        float4 agg[8];
        #pragma unroll
        for (int q = 0; q < 8; ++q) agg[q] = make_float4(0.f,0.f,0.f,0.f);
        int deg = 0;
        for (int d = 0; d < MAX_DEG; ++d) {
            int nb = edge[(size_t)node * MAX_DEG + d];
            if (nb >= 0) {
                ++deg;
                const float4* nr = (const float4*)(x + (size_t)nb * D_IN);
                #pragma unroll
                for (int q = 0; q < 8; ++q) {
                    float4 t = nr[l * 8 + q];
                    agg[q].x += t.x; agg[q].y += t.y;
                    agg[q].z += t.z; agg[q].w += t.w;
                }
            }
        }
        const float inv = 1.0f / (float)deg;
        ushort* dst2 = sH + m * LDS_STRIDE + D_IN + l * 32;
        #pragma unroll
        for (int q = 0; q < 8; ++q) {
            ushort4 p = { (ushort)f2bf(agg[q].x*inv), (ushort)f2bf(agg[q].y*inv),
                          (ushort)f2bf(agg[q].z*inv), (ushort)f2bf(agg[q].w*inv) };
            *(ushort4*)(dst2 + q * 4) = p;
        }
    }
    __syncthreads();
    {
        const int wave = tid >> 6, lane = tid & 63;
        const int quad = lane >> 4, r16 = lane & 15;
        const int mt = wave & 1, nh = wave >> 1;
        f32x4 acc[8];
        #pragma unroll
        for (int j = 0; j < 8; ++j) {
            float bv = bias[(nh * 8 + j) * 16 + r16];
            acc[j] = (f32x4){bv, bv, bv, bv};
        }
        const ushort* arow = sH + (mt * 16 + r16) * LDS_STRIDE + quad * 8;
        #pragma unroll
        for (int ks = 0; ks < D_K / 32; ++ks) {
            bf16x8 a = *(const bf16x8*)(arow + ks * 32);
            #pragma unroll
            for (int j = 0; j < 8; ++j) {
                const int o = (nh * 8 + j) * 16 + r16;
                bf16x8 b = *(const bf16x8*)(Wb + (size_t)o * D_K + ks * 32 + quad * 8);
                acc[j] = __builtin_amdgcn_mfma_f32_16x16x32_bf16(a, b, acc[j], 0, 0, 0);
            }
        }
        #pragma unroll
        for (int j = 0; j < 8; ++j) {
            const int o = (nh * 8 + j) * 16 + r16;
            #pragma unroll
            for (int r = 0; r < 4; ++r) {
                const int row = node0 + mt * 16 + quad * 4 + r;
                out[(size_t)row * D_OUT + o] = acc[j][r];
            }
        }
    }
}

extern "C" void kernel_launch(void* const* d_in, const int* in_sizes, int n_in,
                              void* d_out, int out_size, void* d_ws, size_t ws_size,
                              hipStream_t stream) {
    const float* x    = (const float*)d_in[0];
    const int*   edge = (const int*)d_in[1];
    const float* W    = (const float*)d_in[2];
    const float* bias = (const float*)d_in[3];
    float* out = (float*)d_out;

    const size_t y2_bytes = (size_t)(N_NODES_C + 1) * 256 * 2;    // 51,200,512
    const size_t wb_bytes = (size_t)512 * 256 * 2;                // 262,144
    const int n = in_sizes[0] / D_IN;                             // 100000

    if (ws_size >= y2_bytes + wb_bytes) {
        ushort* y2   = (ushort*)d_ws;
        ushort* Wb2f = (ushort*)((char*)d_ws + y2_bytes);
        cast_w2f_kernel<<<65, 256, 0, stream>>>(W, Wb2f, y2);
        gemm_xw_kernel<<<(n + BM - 1) / BM, 512, 0, stream>>>(x, Wb2f, bias, y2, out);
        gather_add_kernel<<<n / 4, 256, 0, stream>>>(y2, edge, out);
    } else {
        ushort* Wb = (ushort*)d_ws;     // 256 KB
        cast_w_kernel<<<(D_OUT * D_K) / 1024, 256, 0, stream>>>(W, Wb);
        sage_fp32_kernel<<<n / 32, 256, 0, stream>>>(x, edge, Wb, bias, out);
    }
}

// Round 11
// 354.363 us; speedup vs baseline: 1.0848x; 1.0198x over previous
//
#include <hip/hip_runtime.h>
#include <stdint.h>

// SAGEConv via linearity: out = x@W1^T + b + mean_neigh(x)@W2^T
//                             = [x@W1^T + b] + mean_d( (x@W2^T)[e_d] )
// N=100000, MAX_DEG=16, D_IN=256, D_OUT=256
//
// R14: GEMM main loop was VALU-bound: fp32->bf16 conversion at consume time
// = 128 pack2/thread (8x redundant across waves), ~1280 VALU-cyc/wave vs
// 640 MFMA-cyc. Fix: convert ONCE at stage (16 pack2/thread) into a 32KB
// XOR-swizzled bf16 tile; main loop = 4 ds_read_b128 + pinned B dbuf + 16
// MFMA per ks. LDS 64->32KB (launch_bounds(512,4), 2+ blocks/CU). Epilogue:
// two sequential 32KB LDS passes (y1, y2), coalesced 16B stores.
// Gather: unchanged (127.7us, random-row service floor).

#define MAX_DEG 16
#define D_IN 256
#define D_OUT 256
#define N_NODES_C 100000
#define BM 64

typedef __attribute__((ext_vector_type(8))) short bf16x8;   // 8 bf16 = 4 VGPRs
typedef __attribute__((ext_vector_type(4))) float f32x4;

typedef const __attribute__((address_space(1))) void* gas_ptr;
typedef __attribute__((address_space(3))) void* las_ptr;

__device__ __forceinline__ uint32_t f2bf(float f) {
    union { float f; uint32_t u; } v; v.f = f;
    uint32_t u = v.u;
    return (u + 0x7FFFu + ((u >> 16) & 1u)) >> 16;   // RNE; inputs finite
}
__device__ __forceinline__ uint32_t pack2(float lo, float hi) {
    return f2bf(lo) | (f2bf(hi) << 16);
}

// ---- cast W into fragment-major bf16 Wb2f[cg][ks][lane][8]:
//      c = cg*16 + (lane&15), k = ks*32 + (lane>>4)*8 + e
//      (c<256 -> W[c][k] self half; c>=256 -> W[c-256][256+k] neighbor half)
// ---- and zero y2 row N (padding row for edge index -1)
__global__ __launch_bounds__(256) void cast_w2f_kernel(
    const float* __restrict__ W, ushort* __restrict__ Wb2f, ushort* __restrict__ y2)
{
    if (blockIdx.x < 64) {
        const int t = blockIdx.x * 256 + threadIdx.x;   // 0..16383
        const int cg   = t >> 9;          // 0..31
        const int ks   = (t >> 6) & 7;    // 0..7
        const int lane = t & 63;
        const int quad = lane >> 4, r16 = lane & 15;
        const int c = cg * 16 + r16;      // 0..511
        const int k = ks * 32 + quad * 8;
        const float* src = W + (size_t)(c & 255) * 512 + (c >> 8) * 256 + k;
        float4 v0 = ((const float4*)src)[0];
        float4 v1 = ((const float4*)src)[1];
        uint4 p = { pack2(v0.x, v0.y), pack2(v0.z, v0.w),
                    pack2(v1.x, v1.y), pack2(v1.z, v1.w) };
        *(uint4*)(Wb2f + (size_t)t * 8) = p;
    } else {
        if (threadIdx.x < 32) {
            uint4 z = {0u, 0u, 0u, 0u};
            *(uint4*)(y2 + (size_t)N_NODES_C * 256 + threadIdx.x * 8) = z;
        }
    }
}

// pin 4 B-frags (as 16 scalar u32) live at one point
#define PINB4(b0, b1, b2, b3) do {                                          \
    const uint4& u0 = *(const uint4*)&(b0);                                 \
    const uint4& u1 = *(const uint4*)&(b1);                                 \
    const uint4& u2 = *(const uint4*)&(b2);                                 \
    const uint4& u3 = *(const uint4*)&(b3);                                 \
    asm volatile("" :: "v"(u0.x), "v"(u0.y), "v"(u0.z), "v"(u0.w),          \
                       "v"(u1.x), "v"(u1.y), "v"(u1.z), "v"(u1.w),          \
                       "v"(u2.x), "v"(u2.y), "v"(u2.z), "v"(u2.w),          \
                       "v"(u3.x), "v"(u3.y), "v"(u3.z), "v"(u3.w));         \
} while (0)

// ---- Kernel A: 64-row tile. y1[64] = bf16(x@W1^T + b) -> out-row first
// ---- 512B; y2[64] = bf16(x@W2^T) -> ws. x converted ONCE at stage into a
// ---- 32KB XOR-swizzled bf16 LDS tile; B dbuf in regs; 2-pass LDS epilogue.
__global__ __launch_bounds__(512, 4) void gemm_xw_kernel(
    const float* __restrict__ x, const ushort* __restrict__ Wb2f,
    const float* __restrict__ bias, ushort* __restrict__ y2,
    float* __restrict__ out)
{
    __shared__ ushort sT[BM * 256];      // 32,768 B; A-tile, then epilogue

    const int tid = threadIdx.x;
    const int node0 = blockIdx.x * BM;
    const int w = tid >> 6;              // 0..7
    const int lane = tid & 63;
    const int quad = lane >> 4;
    const int r16  = lane & 15;
    const int x7   = r16 & 7;
    const int cb   = (w & 3) * 64;

    // ---- stage: thread owns row = tid>>3, 32 floats at l*32; convert once,
    // ---- write 4 bf16 16B-chunks c = l*4+q at slot (c ^ (row&7)).
    {
        const int row = tid >> 3, l = tid & 7;
        const int rg = node0 + row;
        const float* src = x + (size_t)(rg < N_NODES_C ? rg : N_NODES_C - 1) * D_IN + l * 32;
        f32x4 v[8];
        #pragma unroll
        for (int q = 0; q < 8; ++q) v[q] = ((const f32x4*)src)[q];
        {   // single pin: all 8 loads issued before any convert
            const uint4& a0 = *(const uint4*)&v[0]; const uint4& a1 = *(const uint4*)&v[1];
            const uint4& a2 = *(const uint4*)&v[2]; const uint4& a3 = *(const uint4*)&v[3];
            const uint4& a4 = *(const uint4*)&v[4]; const uint4& a5 = *(const uint4*)&v[5];
            const uint4& a6 = *(const uint4*)&v[6]; const uint4& a7 = *(const uint4*)&v[7];
            asm volatile("" :: "v"(a0.x),"v"(a0.y),"v"(a0.z),"v"(a0.w),
                               "v"(a1.x),"v"(a1.y),"v"(a1.z),"v"(a1.w),
                               "v"(a2.x),"v"(a2.y),"v"(a2.z),"v"(a2.w),
                               "v"(a3.x),"v"(a3.y),"v"(a3.z),"v"(a3.w),
                               "v"(a4.x),"v"(a4.y),"v"(a4.z),"v"(a4.w),
                               "v"(a5.x),"v"(a5.y),"v"(a5.z),"v"(a5.w),
                               "v"(a6.x),"v"(a6.y),"v"(a6.z),"v"(a6.w),
                               "v"(a7.x),"v"(a7.y),"v"(a7.z),"v"(a7.w));
        }
        #pragma unroll
        for (int q = 0; q < 4; ++q) {
            uint4 p = { pack2(v[2*q].x, v[2*q].y), pack2(v[2*q].z, v[2*q].w),
                        pack2(v[2*q+1].x, v[2*q+1].y), pack2(v[2*q+1].z, v[2*q+1].w) };
            const int c = l * 4 + q;
            *(uint4*)((char*)sT + row * 512 + ((c ^ (row & 7)) << 4)) = p;
        }
    }

    // bias for this wave's 4 col-frags (used only if w<4)
    float bv[4];
    #pragma unroll
    for (int j = 0; j < 4; ++j)
        bv[j] = bias[cb + j * 16 + r16];

    __syncthreads();

    f32x4 acc[4][4];                     // [row strip][col frag]
    #pragma unroll
    for (int s = 0; s < 4; ++s)
        #pragma unroll
        for (int j = 0; j < 4; ++j)
            acc[s][j] = (f32x4){0.f, 0.f, 0.f, 0.f};

    const ushort* bp = Wb2f + ((size_t)(w * 4) * 8 + 0) * 64 * 8 + lane * 8;

    // B double-buffer: load ks=0, pin; per ks load ks+1, pin, MFMA current
    bf16x8 bcur[4], bnxt[4];
    #pragma unroll
    for (int j = 0; j < 4; ++j)
        bcur[j] = *(const bf16x8*)(bp + ((size_t)j * 8 + 0) * 64 * 8);
    PINB4(bcur[0], bcur[1], bcur[2], bcur[3]);

    #pragma unroll
    for (int ks = 0; ks < D_IN / 32; ++ks) {
        if (ks < D_IN / 32 - 1) {
            #pragma unroll
            for (int j = 0; j < 4; ++j)
                bnxt[j] = *(const bf16x8*)(bp + ((size_t)j * 8 + ks + 1) * 64 * 8);
            PINB4(bnxt[0], bnxt[1], bnxt[2], bnxt[3]);
        }
        // A-frags: row = s*16+r16, chunk ch = ks*4+quad, slot = ch ^ x7
        bf16x8 afr[4];
        #pragma unroll
        for (int s = 0; s < 4; ++s)
            afr[s] = *(const bf16x8*)((const char*)sT + (s * 16 + r16) * 512 +
                                      (((ks * 4 + quad) ^ x7) << 4));
        #pragma unroll
        for (int j = 0; j < 4; ++j) {
            acc[0][j] = __builtin_amdgcn_mfma_f32_16x16x32_bf16(afr[0], bcur[j], acc[0][j], 0, 0, 0);
            acc[1][j] = __builtin_amdgcn_mfma_f32_16x16x32_bf16(afr[1], bcur[j], acc[1][j], 0, 0, 0);
            acc[2][j] = __builtin_amdgcn_mfma_f32_16x16x32_bf16(afr[2], bcur[j], acc[2][j], 0, 0, 0);
            acc[3][j] = __builtin_amdgcn_mfma_f32_16x16x32_bf16(afr[3], bcur[j], acc[3][j], 0, 0, 0);
        }
        #pragma unroll
        for (int j = 0; j < 4; ++j) bcur[j] = bnxt[j];
    }

    // ---- epilogue: two sequential 32KB LDS passes (reuse sT).
    // pass 1: y1 = self + bias (waves 0..3) -> out-row head (bf16)
    __syncthreads();
    if (w < 4) {
        #pragma unroll
        for (int j = 0; j < 4; ++j) {
            const int c = cb + j * 16 + r16;
            #pragma unroll
            for (int s = 0; s < 4; ++s)
                #pragma unroll
                for (int r = 0; r < 4; ++r) {
                    const int row = s * 16 + quad * 4 + r;
                    sT[row * 256 + ((((c >> 3) ^ (row & 7)) << 3) | (c & 7))] =
                        (ushort)f2bf(acc[s][j][r] + bv[j]);
                }
        }
    }
    __syncthreads();
    #pragma unroll
    for (int t = 0; t < 4; ++t) {
        const int idx = t * 512 + tid;        // 0..2047 16B-chunks
        const int row = idx >> 5, ch = idx & 31;
        const int rg = node0 + row;
        if (rg < N_NODES_C) {
            const uint4 v = *(const uint4*)(sT + row * 256 + ((ch ^ (row & 7)) << 3));
            *(uint4*)((char*)(out + (size_t)rg * D_OUT) + ch * 16) = v;
        }
    }
    // pass 2: y2 (waves 4..7) -> ws (bf16)
    __syncthreads();
    if (w >= 4) {
        #pragma unroll
        for (int j = 0; j < 4; ++j) {
            const int c = cb + j * 16 + r16;
            #pragma unroll
            for (int s = 0; s < 4; ++s)
                #pragma unroll
                for (int r = 0; r < 4; ++r) {
                    const int row = s * 16 + quad * 4 + r;
                    sT[row * 256 + ((((c >> 3) ^ (row & 7)) << 3) | (c & 7))] =
                        (ushort)f2bf(acc[s][j][r]);
                }
        }
    }
    __syncthreads();
    #pragma unroll
    for (int t = 0; t < 4; ++t) {
        const int idx = t * 512 + tid;
        const int row = idx >> 5, ch = idx & 31;
        const int rg = node0 + row;
        if (rg < N_NODES_C) {
            const uint4 v = *(const uint4*)(sT + row * 256 + ((ch ^ (row & 7)) << 3));
            *(uint4*)((char*)y2 + (size_t)rg * 512 + ch * 16) = v;
        }
    }
}

// ---- Kernel B (unchanged): one node per wave.
// out[i] = y1[i] + inv*sum y2[e_d]. 8 async global_load_lds row-pair copies
// into a private 8KB LDS slice; one vmcnt(0); conflict-free readback.
__global__ __launch_bounds__(256, 5) void gather_add_kernel(
    const ushort* __restrict__ y2, const int* __restrict__ edge,
    float* __restrict__ out)
{
    __shared__ char sBuf[4 * 8 * 1024];                  // 32 KB: 4 waves x 8KB

    const int w4   = threadIdx.x >> 6;                   // wave in block
    const int lane = threadIdx.x & 63;
    const int i = blockIdx.x * 4 + w4;                   // node, 0..99999

    const int e = edge[(size_t)i * MAX_DEG + (lane & 15)];
    const unsigned long long vm = __ballot(e >= 0);
    const int deg = (int)__popcll(vm & 0xFFFFull);       // >= 1
    const float inv = 1.0f / (float)deg;

    const uint32_t off_me = (uint32_t)(e < 0 ? N_NODES_C : e) * 512u;  // row bytes
    const char* yb = (const char*)y2;
    const uint32_t coff = (uint32_t)((lane & 31) * 16);  // 16B slot within 512B row
    const int half = lane >> 5;

    // y1 prefetch: 4 bf16 (8B) covering this lane's 4 output floats
    const int cw = (lane & 31) * 8 + half * 4;           // float col base
    float* op = out + (size_t)i * D_OUT + cw;
    const uint2 y1p = *(const uint2*)((const char*)(out + (size_t)i * D_OUT) + cw * 2);

    // issue 8 async row-pair copies: chunk k = rows e_{2k} (lanes 0..31)
    // and e_{2k+1} (lanes 32..63); LDS dest = wavebase + k*1024 + lane*16
    char* lw = sBuf + (size_t)w4 * 8192;
    #pragma unroll
    for (int k = 0; k < 8; ++k) {
        const uint32_t ro = (uint32_t)__shfl((int)off_me, 2 * k + half, 64);
        const char* gsrc = yb + (size_t)(ro + coff);
        __builtin_amdgcn_global_load_lds((gas_ptr)gsrc, (las_ptr)(lw + k * 1024),
                                         16, 0, 0);
    }
    asm volatile("s_waitcnt vmcnt(0)" ::: "memory");
    __builtin_amdgcn_sched_barrier(0);

    float a[8];
    #pragma unroll
    for (int q = 0; q < 8; ++q) a[q] = 0.f;
    #pragma unroll
    for (int k = 0; k < 8; ++k) {
        uint4 g = *(const uint4*)(lw + k * 1024 + lane * 16);
        uint32_t u[4] = { g.x, g.y, g.z, g.w };
        #pragma unroll
        for (int q = 0; q < 4; ++q) {
            union { uint32_t ui; float f; } lo, hi;
            lo.ui = u[q] << 16;
            hi.ui = u[q] & 0xFFFF0000u;
            a[2*q]   += lo.f;
            a[2*q+1] += hi.f;
        }
    }
    // combine even-d half (lanes<32) with odd-d half (lanes>=32)
    #pragma unroll
    for (int q = 0; q < 8; ++q) a[q] += __shfl_xor(a[q], 32, 64);

    // unpack y1 bf16 -> fp32 and finalize: out = y1 + inv * sum
    const int q0 = half * 4;
    union { uint32_t ui; float f; } c0, c1, c2, c3;
    c0.ui = y1p.x << 16; c1.ui = y1p.x & 0xFFFF0000u;
    c2.ui = y1p.y << 16; c3.ui = y1p.y & 0xFFFF0000u;
    float4 r;
    r.x = c0.f + inv * a[q0 + 0];
    r.y = c1.f + inv * a[q0 + 1];
    r.z = c2.f + inv * a[q0 + 2];
    r.w = c3.f + inv * a[q0 + 3];
    *(float4*)op = r;
}

// ---------------- fallback (small ws): fp32-gather path ----------------
#define D_K 512
#define LDS_STRIDE 520

__global__ __launch_bounds__(256) void cast_w_kernel(const float* __restrict__ W,
                                                     ushort* __restrict__ Wb) {
    int i = (blockIdx.x * 256 + threadIdx.x) * 4;
    float4 v = *(const float4*)(W + i);
    ushort4 p = { (ushort)f2bf(v.x), (ushort)f2bf(v.y),
                  (ushort)f2bf(v.z), (ushort)f2bf(v.w) };
    *(ushort4*)(Wb + i) = p;
}

__global__ __launch_bounds__(256) void sage_fp32_kernel(
    const float* __restrict__ x, const int* __restrict__ edge,
    const ushort* __restrict__ Wb, const float* __restrict__ bias,
    float* __restrict__ out)
{
    __shared__ ushort sH[32 * LDS_STRIDE];
    const int tid = threadIdx.x;
    const int node0 = blockIdx.x * 32;
    {
        const int m = tid >> 3, l = tid & 7;
        const int node = node0 + m;
        const float4* xrow = (const float4*)(x + (size_t)node * D_IN);
        ushort* dst = sH + m * LDS_STRIDE + l * 32;
        #pragma unroll
        for (int q = 0; q < 8; ++q) {
            float4 v = xrow[l * 8 + q];
            ushort4 p = { (ushort)f2bf(v.x), (ushort)f2bf(v.y),
                          (ushort)f2bf(v.z), (ushort)f2bf(v.w) };
            *(ushort4*)(dst + q * 4) = p;
        }
        float4 agg[8];
        #pragma unroll
        for (int q = 0; q < 8; ++q) agg[q] = make_float4(0.f,0.f,0.f,0.f);
        int deg = 0;
        for (int d = 0; d < MAX_DEG; ++d) {
            int nb = edge[(size_t)node * MAX_DEG + d];
            if (nb >= 0) {
                ++deg;
                const float4* nr = (const float4*)(x + (size_t)nb * D_IN);
                #pragma unroll
                for (int q = 0; q < 8; ++q) {
                    float4 t = nr[l * 8 + q];
                    agg[q].x += t.x; agg[q].y += t.y;
                    agg[q].z += t.z; agg[q].w += t.w;
                }
            }
        }
        const float inv = 1.0f / (float)deg;
        ushort* dst2 = sH + m * LDS_STRIDE + D_IN + l * 32;
        #pragma unroll
        for (int q = 0; q < 8; ++q) {
            ushort4 p = { (ushort)f2bf(agg[q].x*inv), (ushort)f2bf(agg[q].y*inv),
                          (ushort)f2bf(agg[q].z*inv), (ushort)f2bf(agg[q].w*inv) };
            *(ushort4*)(dst2 + q * 4) = p;
        }
    }
    __syncthreads();
    {
        const int wave = tid >> 6, lane = tid & 63;
        const int quad = lane >> 4, r16 = lane & 15;
        const int mt = wave & 1, nh = wave >> 1;
        f32x4 acc[8];
        #pragma unroll
        for (int j = 0; j < 8; ++j) {
            float bv = bias[(nh * 8 + j) * 16 + r16];
            acc[j] = (f32x4){bv, bv, bv, bv};
        }
        const ushort* arow = sH + (mt * 16 + r16) * LDS_STRIDE + quad * 8;
        #pragma unroll
        for (int ks = 0; ks < D_K / 32; ++ks) {
            bf16x8 a = *(const bf16x8*)(arow + ks * 32);
            #pragma unroll
            for (int j = 0; j < 8; ++j) {
                const int o = (nh * 8 + j) * 16 + r16;
                bf16x8 b = *(const bf16x8*)(Wb + (size_t)o * D_K + ks * 32 + quad * 8);
                acc[j] = __builtin_amdgcn_mfma_f32_16x16x32_bf16(a, b, acc[j], 0, 0, 0);
            }
        }
        #pragma unroll
        for (int j = 0; j < 8; ++j) {
            const int o = (nh * 8 + j) * 16 + r16;
            #pragma unroll
            for (int r = 0; r < 4; ++r) {
                const int row = node0 + mt * 16 + quad * 4 + r;
                out[(size_t)row * D_OUT + o] = acc[j][r];
            }
        }
    }
}

extern "C" void kernel_launch(void* const* d_in, const int* in_sizes, int n_in,
                              void* d_out, int out_size, void* d_ws, size_t ws_size,
                              hipStream_t stream) {
    const float* x    = (const float*)d_in[0];
    const int*   edge = (const int*)d_in[1];
    const float* W    = (const float*)d_in[2];
    const float* bias = (const float*)d_in[3];
    float* out = (float*)d_out;

    const size_t y2_bytes = (size_t)(N_NODES_C + 1) * 256 * 2;    // 51,200,512
    const size_t wb_bytes = (size_t)512 * 256 * 2;                // 262,144
    const int n = in_sizes[0] / D_IN;                             // 100000

    if (ws_size >= y2_bytes + wb_bytes) {
        ushort* y2   = (ushort*)d_ws;
        ushort* Wb2f = (ushort*)((char*)d_ws + y2_bytes);
        cast_w2f_kernel<<<65, 256, 0, stream>>>(W, Wb2f, y2);
        gemm_xw_kernel<<<(n + BM - 1) / BM, 512, 0, stream>>>(x, Wb2f, bias, y2, out);
        gather_add_kernel<<<n / 4, 256, 0, stream>>>(y2, edge, out);
    } else {
        ushort* Wb = (ushort*)d_ws;     // 256 KB
        cast_w_kernel<<<(D_OUT * D_K) / 1024, 256, 0, stream>>>(W, Wb);
        sage_fp32_kernel<<<n / 32, 256, 0, stream>>>(x, edge, Wb, bias, out);
    }
}